// Round 3
// baseline (325.652 us; speedup 1.0000x reference)
//
#include <hip/hip_runtime.h>
#include <math.h>

#define HW 9216
#define Hh 96
#define Ww 96
#define PHW 9604      // 98*98 padded (xpad1/hpa/hpb)
#define QSLOTS 9604   // 98*98 quad-corner slots (xdp), each 32 shorts = 64B

typedef __attribute__((ext_vector_type(8))) short bh8;
typedef __attribute__((ext_vector_type(4))) short bh4;
typedef __attribute__((ext_vector_type(4))) float f32x4;
typedef __attribute__((ext_vector_type(2))) float f32x2;
typedef __attribute__((ext_vector_type(4))) int i32x4;
union bh8i { bh8 v; i32x4 i; };

__device__ __forceinline__ short f2bf(float f) {
    union { float f; unsigned u; } v; v.f = f;
    unsigned r = v.u + 0x7FFFu + ((v.u >> 16) & 1u);
    return (short)(r >> 16);
}
__device__ __forceinline__ float bf2f(short s) {
    union { unsigned u; float f; } v; v.u = ((unsigned)(unsigned short)s) << 16;
    return v.f;
}
__device__ __forceinline__ float lo_bf(unsigned u) {
    union { unsigned u; float f; } v; v.u = u << 16; return v.f;
}
__device__ __forceinline__ float hi_bf(unsigned u) {
    union { unsigned u; float f; } v; v.u = u & 0xFFFF0000u; return v.f;
}
// packed RNE f32->bf16x2 (identical rounding to f2bf), 1 instr
__device__ __forceinline__ int cvt_pk_bf16(float lo, float hi) {
    int r;
    asm("v_cvt_pk_bf16_f32 %0, %1, %2" : "=v"(r) : "v"(lo), "v"(hi));
    return r;
}

// ---------------------------------------------------------------------------
// Fused misc prep: pad-border zeroing (xpad1/hpa/hpb), xdp border-slot
// zeroing (quad-corner layout), and all weight prep.
__global__ void prep_misc(short* __restrict__ xpad1, short* __restrict__ hpa,
                          short* __restrict__ hpb, short* __restrict__ xdp,
                          const float* __restrict__ ow0, const float* __restrict__ ow1,
                          const float* __restrict__ ow2, const float* __restrict__ ow3,
                          const float* __restrict__ wd,
                          short* __restrict__ wb0, short* __restrict__ wb1,
                          short* __restrict__ wb2, short* __restrict__ wb3,
                          short* __restrict__ wbd) {
    int i = blockIdx.x * 256 + threadIdx.x;
    const int z1 = 4 * 388 * 224, z2 = 4 * 388 * 64;
    // --- segment A: borders of xpad1/hpa/hpb
    if (i < z1 + 2 * z2) {
        short* p; int C;
        if (i < z1) { p = xpad1; C = 224; }
        else if (i < z1 + z2) { p = hpa; C = 64; i -= z1; }
        else { p = hpb; C = 64; i -= z1 + z2; }
        int c = i % C;
        int r = i / C;
        int b = r / 388, pid = r - b * 388;
        int row, col;
        if (pid < 98)       { row = 0;  col = pid; }
        else if (pid < 196) { row = 97; col = pid - 98; }
        else if (pid < 292) { row = pid - 196 + 1; col = 0; }
        else                { row = pid - 292 + 1; col = 97; }
        p[((size_t)b * PHW + row * 98 + col) * C + c] = 0;
        return;
    }
    i -= z1 + 2 * z2;
    // --- segment B: border slots of xdp (y in {0,96,97} or x in {0,96,97}),
    // 579 slots per (b,g), 4 x 16B pieces per slot. Interior slots are fully
    // written by pack_all, so no memset needed.
    const int zr = 64 * 579 * 4;
    if (i < zr) {
        int piece = i & 3;
        int r2 = i >> 2;
        int s = r2 % 579, bg = r2 / 579;
        int y, x;
        if (s < 98)       { y = 0;  x = s; }
        else if (s < 196) { y = 96; x = s - 98; }
        else if (s < 294) { y = 97; x = s - 196; }
        else {
            int s2 = s - 294;
            int xi = s2 / 95;
            x = (xi == 0) ? 0 : ((xi == 1) ? 96 : 97);
            y = 1 + s2 - xi * 95;
        }
        *(bh8*)&xdp[(((size_t)bg * QSLOTS) + y * 98 + x) * 32 + piece * 8] =
            (bh8){0, 0, 0, 0, 0, 0, 0, 0};
        return;
    }
    i -= zr;
    // --- segment C: weights
    const int n0 = 64 * 9 * 224, n1 = 64 * 9 * 64, n3 = 448 * 9 * 64, nd = 144 * 64 * 8;
    if (i < n0) {
        int co = i / (9 * 224); int r = i - co * (9 * 224);
        int tap = r / 224, ci = r - tap * 224;
        wb0[i] = f2bf(ci < 196 ? ow0[(co * 196 + ci) * 9 + tap] : 0.f);
        return;
    }
    i -= n0;
    if (i < n1) {
        int co = i / (9 * 64); int r = i - co * (9 * 64);
        int tap = r / 64, ci = r - tap * 64;
        wb1[i] = f2bf(ow1[(co * 64 + ci) * 9 + tap]);
        return;
    }
    i -= n1;
    if (i < n1) {
        int co = i / (9 * 64); int r = i - co * (9 * 64);
        int tap = r / 64, ci = r - tap * 64;
        wb2[i] = f2bf(ow2[(co * 64 + ci) * 9 + tap]);
        return;
    }
    i -= n1;
    if (i < n3) {
        int co = i / (9 * 64); int r = i - co * (9 * 64);
        int tap = r / 64, ci = r - tap * 64;
        wb3[i] = f2bf(co < 432 ? ow3[(co * 64 + ci) * 9 + tap] : 0.f);
        return;
    }
    i -= n3;
    if (i < nd) {
        // deform weight relayout: [gt][co][c]  (gt = g*9+tap, 144 x 64 x 8)
        int gt = i >> 9, r = i & 511;
        int co = r >> 3, c = r & 7;
        int g = gt / 9, tap = gt - g * 9;
        wbd[i] = f2bf(wd[(co * 128 + g * 8 + c) * 9 + tap]);
    }
}

// ---------------------------------------------------------------------------
// Fused packers. y<7: concat->xpad1 (ct=y). y>=7: x->xdp quad-corner layout:
// slot (g,y,x) = 64B holding the 2x2 neighborhood (padded rows y,y+1, cols
// x,x+1) x 8ch. Each pixel is written to 4 slots (as each corner role).
__global__ void pack_all(const float* __restrict__ extra,
                         const float* __restrict__ f1,
                         const float* __restrict__ f2,
                         const float* __restrict__ x,
                         short* __restrict__ xp,
                         short* __restrict__ xdp) {
    __shared__ float t[32][33];
    const int tid = threadIdx.x, tx = tid & 31, ty = tid >> 5;
    const int pt = blockIdx.x, b = blockIdx.z;
    if (blockIdx.y < 7) {
        const int ct = blockIdx.y;
#pragma unroll
        for (int j = 0; j < 4; ++j) {
            int ch = ct * 32 + ty + j * 8;
            int p = pt * 32 + tx;
            float v = 0.f;
            if (ch < 192)      v = extra[(b * 192 + ch) * HW + p];
            else if (ch < 194) v = f1[(b * 2 + ch - 192) * HW + p];
            else if (ch < 196) v = f2[(b * 2 + ch - 194) * HW + p];
            t[ty + j * 8][tx] = v;
        }
        __syncthreads();
#pragma unroll
        for (int j = 0; j < 4; ++j) {
            int pr = ty + j * 8;
            int p = pt * 32 + pr;
            int r = p / 96, c = p - r * 96;
            xp[((size_t)b * PHW + (r + 1) * 98 + (c + 1)) * 224 + ct * 32 + tx] =
                f2bf(t[tx][pr]);
        }
    } else {
        const int ct = blockIdx.y - 7;
#pragma unroll
        for (int j = 0; j < 4; ++j) {
            int ch = ct * 32 + ty + j * 8;
            t[ty + j * 8][tx] = x[((size_t)b * 128 + ch) * HW + pt * 32 + tx];
        }
        __syncthreads();
        if (tid < 128) {
            int oct = tid >> 5, p = tid & 31;
            int g = ct * 4 + oct;
            int pix = pt * 32 + p;
            int r = pix / 96, c = pix - r * 96;
            bh8 v;
#pragma unroll
            for (int cc = 0; cc < 8; ++cc) v[cc] = f2bf(t[oct * 8 + cc][p]);
            size_t sb = ((size_t)b * 16 + g) * QSLOTS;
            int pr = r + 1, pc = c + 1;     // padded coords, 1..96
            // corner roles: q = cy*2+cx at offset q*8 shorts within slot
            *(bh8*)&xdp[(sb + pr * 98 + pc) * 32 + 0]        = v;  // (0,0)
            *(bh8*)&xdp[(sb + pr * 98 + pc - 1) * 32 + 8]    = v;  // (0,1)
            *(bh8*)&xdp[(sb + (pr - 1) * 98 + pc) * 32 + 16] = v;  // (1,0)
            *(bh8*)&xdp[(sb + (pr - 1) * 98 + pc - 1) * 32 + 24] = v; // (1,1)
        }
    }
}

// ---------------------------------------------------------------------------
// conv1-3 (round-6 structure): block = 4 waves x (16px x 64co), weight chunk
// staged in LDS per 32-cin chunk, B-frags direct 16B global loads.
// ---------------------------------------------------------------------------
template<int CINP, int KCH>
__launch_bounds__(256)
__global__ void conv_mfma(const short* __restrict__ xp,
                          const short* __restrict__ wb,
                          const float* __restrict__ bias,
                          short* __restrict__ o1) {
    __shared__ __attribute__((aligned(16))) short smA[9 * 64 * 32];
    const int tid = threadIdx.x;
    const int lane = tid & 63, wv = tid >> 6;
    const int q = lane >> 4, l15 = lane & 15;
    const int b = blockIdx.y;
    const int pix0 = blockIdx.x * 64 + wv * 16;
    const int soh = pix0 / 96, sow = pix0 - (pix0 / 96) * 96;

    const short* bp = xp + ((size_t)b * PHW + soh * 98 + sow + l15) * CINP + q * 8;

    const int sco = tid >> 2, sqq = tid & 3;
    const short* wsrc = wb + (size_t)sco * (9 * CINP) + sqq * 8;

    f32x4 acc[4];
#pragma unroll
    for (int t = 0; t < 4; ++t) acc[t] = (f32x4){0.f, 0.f, 0.f, 0.f};

    for (int p = 0; p < KCH; ++p) {
        __syncthreads();
        bh8 wtmp[9];
#pragma unroll
        for (int tap = 0; tap < 9; ++tap)
            wtmp[tap] = *(const bh8*)(wsrc + tap * CINP + p * 32);
#pragma unroll
        for (int tap = 0; tap < 9; ++tap)
            *(bh8*)&smA[tap * 2048 + sco * 32 + sqq * 8] = wtmp[tap];
        __syncthreads();
#pragma unroll
        for (int tap = 0; tap < 9; ++tap) {
            const int ky = tap / 3, kx = tap - (tap / 3) * 3;
            bh8 bf = *(const bh8*)(bp + (ky * 98 + kx) * CINP + p * 32);
#pragma unroll
            for (int t = 0; t < 4; ++t) {
                bh8 af = *(const bh8*)&smA[tap * 2048 + (t * 16 + l15) * 32 + q * 8];
                acc[t] = __builtin_amdgcn_mfma_f32_16x16x32_bf16(af, bf, acc[t], 0, 0, 0);
            }
        }
    }

    size_t base = ((size_t)b * PHW + (soh + 1) * 98 + sow + l15 + 1) * 64;
#pragma unroll
    for (int t = 0; t < 4; ++t) {
        bh4 v4;
#pragma unroll
        for (int r = 0; r < 4; ++r) {
            int co = t * 16 + q * 4 + r;
            float v = acc[t][r] + bias[co];
            v = (v >= 0.f) ? v : 0.1f * v;
            v4[r] = f2bf(v);
        }
        *(bh4*)(o1 + base + t * 16 + q * 4) = v4;
    }
}

// ---------------------------------------------------------------------------
// conv4 in the conv_mfma structure: grid (144,4,7), bz = 64-co block. Weights
// LDS-staged once per 32-ch chunk (4 barriers/block vs 18 in the old tiled
// GEMM), activations loaded per-lane direct from global (hpa is L3-resident).
// Epilogue: offset channels -> 10*tanh + flow, f32x2 pair store; mask
// channels -> sigmoid -> bf16.
// ---------------------------------------------------------------------------
__launch_bounds__(256)
__global__ void conv4_mfma(const short* __restrict__ xp,
                           const short* __restrict__ wb,   // wb3: [co][tap][64]
                           const float* __restrict__ bias,
                           float* __restrict__ offp,
                           short* __restrict__ maskb,
                           const float* __restrict__ flow1,
                           const float* __restrict__ flow2) {
    __shared__ __attribute__((aligned(16))) short smA[9 * 64 * 32];
    const int tid = threadIdx.x;
    const int lane = tid & 63, wv = tid >> 6;
    const int q = lane >> 4, l15 = lane & 15;
    const int b = blockIdx.y;
    const int cob = blockIdx.z * 64;
    const int pix0 = blockIdx.x * 64 + wv * 16;
    const int soh = pix0 / 96, sow = pix0 - (pix0 / 96) * 96;

    const short* bp = xp + ((size_t)b * PHW + soh * 98 + sow + l15) * 64 + q * 8;

    const int sco = tid >> 2, sqq = tid & 3;
    const short* wsrc = wb + (size_t)(cob + sco) * 576 + sqq * 8;

    f32x4 acc[4];
#pragma unroll
    for (int t = 0; t < 4; ++t) acc[t] = (f32x4){0.f, 0.f, 0.f, 0.f};

    for (int p = 0; p < 2; ++p) {
        __syncthreads();
        bh8 wtmp[9];
#pragma unroll
        for (int tap = 0; tap < 9; ++tap)
            wtmp[tap] = *(const bh8*)(wsrc + tap * 64 + p * 32);
#pragma unroll
        for (int tap = 0; tap < 9; ++tap)
            *(bh8*)&smA[tap * 2048 + sco * 32 + sqq * 8] = wtmp[tap];
        __syncthreads();
#pragma unroll
        for (int tap = 0; tap < 9; ++tap) {
            const int ky = tap / 3, kx = tap - (tap / 3) * 3;
            bh8 bf = *(const bh8*)(bp + (ky * 98 + kx) * 64 + p * 32);
#pragma unroll
            for (int t = 0; t < 4; ++t) {
                bh8 af = *(const bh8*)&smA[tap * 2048 + (t * 16 + l15) * 32 + q * 8];
                acc[t] = __builtin_amdgcn_mfma_f32_16x16x32_bf16(af, bf, acc[t], 0, 0, 0);
            }
        }
    }

    const int pix = pix0 + l15;
#pragma unroll
    for (int t = 0; t < 4; ++t) {
        int cb0 = cob + t * 16 + q * 4;
        if (cb0 < 288) {
            const float* fl = (cb0 < 144) ? flow1 : flow2;
            float fe = fl[(b * 2 + 1) * HW + pix];
            float fo = fl[(b * 2) * HW + pix];
            float t0 = 10.f * tanhf(acc[t][0] + bias[cb0 + 0]) + fe;
            float t1 = 10.f * tanhf(acc[t][1] + bias[cb0 + 1]) + fo;
            float t2 = 10.f * tanhf(acc[t][2] + bias[cb0 + 2]) + fe;
            float t3 = 10.f * tanhf(acc[t][3] + bias[cb0 + 3]) + fo;
            size_t p0 = ((size_t)b * 144 + (cb0 >> 1)) * HW + pix;
            *(f32x2*)&offp[p0 * 2] = (f32x2){t0, t1};
            *(f32x2*)&offp[(p0 + HW) * 2] = (f32x2){t2, t3};
        } else {
#pragma unroll
            for (int r = 0; r < 4; ++r) {
                int chn = cb0 + r;
                if (chn < 432) {
                    float v = acc[t][r] + bias[chn];
                    maskb[((size_t)b * 144 + (chn - 288)) * HW + pix] =
                        f2bf(1.f / (1.f + expf(-v)));
                }
            }
        }
    }
}

// ---------------------------------------------------------------------------
// Deform, corner-in-K scheme: MFMA K = 4 corners x 8ch of ONE group-tap.
// Lane (q,l15): corner q, pixel l15. Corner loads are 4-lane coalesced from
// 64B-aligned quad-corner slots; A (wbd) is corner-replicated so loads are
// 16-lane contiguous. The bilinear corner sum happens inside the MFMA.
// ---------------------------------------------------------------------------
__launch_bounds__(256)
__global__ void deform_mfma(const short* __restrict__ xdp,
                            const float* __restrict__ offp,
                            const short* __restrict__ maskb,
                            const short* __restrict__ wbd,
                            const float* __restrict__ bias,
                            float* __restrict__ out) {
    __shared__ float red[4][1024];
    const int tid = threadIdx.x;
    const int lane = tid & 63, wv = tid >> 6;
    const int q = lane >> 4, l15 = lane & 15;
    const int blk = blockIdx.x;
    const int xs = blk & 7, idx = blk >> 3;
    const int b = xs >> 1;
    const int pix0 = ((xs & 1) * 288 + idx) * 16;
    const int pix = pix0 + l15;
    const int h = pix / 96, w = pix - (pix / 96) * 96;

    const short* xb = xdp + (size_t)b * 16 * QSLOTS * 32;

    f32x4 acc[4];
#pragma unroll
    for (int t = 0; t < 4; ++t) acc[t] = (f32x4){0.f, 0.f, 0.f, 0.f};

#pragma unroll
    for (int chunk = 0; chunk < 4; ++chunk) {
        const int g = wv * 4 + chunk;     // this wave's group for this chunk
        const float* opp = offp + (((size_t)b * 144 + g * 9) * HW + pix) * 2;
        const short* mp  = maskb + ((size_t)b * 144 + g * 9) * HW + pix;

        // 9 offset/mask loads (q-duplicated, 16-pixel contiguous -> 1-2 lines)
        f32x2 dxy[9];
        float mk[9];
#pragma unroll
        for (int i = 0; i < 9; ++i) {
            dxy[i] = *(const f32x2*)(opp + (size_t)i * HW * 2);
            mk[i]  = bf2f(mp[(size_t)i * HW]);
        }

        // per-lane: slot offset + this corner's bilinear weight
        int soff[9];
        float wq[9];
#pragma unroll
        for (int i = 0; i < 9; ++i) {
            float py = dxy[i][0] + (float)(i / 3) + (float)h - 1.f;
            float px = dxy[i][1] + (float)(i % 3) + (float)w - 1.f;
            py = fminf(fmaxf(py, -1.f), 96.f);
            px = fminf(fmaxf(px, -1.f), 96.f);
            float y0f = floorf(py), x0f = floorf(px);
            float wy1 = py - y0f, wx1 = px - x0f;
            int yp = (int)y0f + 1, xp = (int)x0f + 1;   // slot coords 0..97
            soff[i] = ((g * QSLOTS + yp * 98 + xp) << 5) + q * 8;
            float wy = (q & 2) ? wy1 : (1.f - wy1);
            float wx = (q & 1) ? wx1 : (1.f - wx1);
            wq[i] = wy * wx * mk[i];
        }

#pragma unroll
        for (int i = 0; i < 9; ++i) {
            bh8i cv;
            cv.v = *(const bh8*)(xb + soff[i]);
            const f32x2 w2 = (f32x2){wq[i], wq[i]};
            bh8i bf;
#pragma unroll
            for (int k2 = 0; k2 < 4; ++k2) {
                unsigned u = (unsigned)cv.i[k2];
                f32x2 pv = (f32x2){lo_bf(u), hi_bf(u)} * w2;
                bf.i[k2] = cvt_pk_bf16(pv[0], pv[1]);
            }
            const int gt = g * 9 + i;
            const short* ap = wbd + ((size_t)gt * 64 + l15) * 8;
#pragma unroll
            for (int t = 0; t < 4; ++t) {
                bh8 af = *(const bh8*)(ap + t * 128);   // +t*16 co, 8 ch each
                acc[t] = __builtin_amdgcn_mfma_f32_16x16x32_bf16(af, bf.v, acc[t], 0, 0, 0);
            }
        }
    }

#pragma unroll
    for (int t = 0; t < 4; ++t)
#pragma unroll
        for (int r = 0; r < 4; ++r)
            red[wv][(t * 16 + q * 4 + r) * 16 + l15] = acc[t][r];
    __syncthreads();
    for (int e = tid; e < 1024; e += 256) {
        int co = e >> 4, pl = e & 15;
        float v = red[0][e] + red[1][e] + red[2][e] + red[3][e] + bias[co];
        out[((size_t)b * 64 + co) * HW + pix0 + pl] = v;
    }
}

// ---------------------------------------------------------------------------
extern "C" void kernel_launch(void* const* d_in, const int* in_sizes, int n_in,
                              void* d_out, int out_size, void* d_ws, size_t ws_size,
                              hipStream_t stream) {
    const float* x      = (const float*)d_in[0];
    const float* extra  = (const float*)d_in[1];
    const float* flow1  = (const float*)d_in[2];
    const float* flow2  = (const float*)d_in[3];
    const float* weight = (const float*)d_in[4];
    const float* bias   = (const float*)d_in[5];
    const float* ow0    = (const float*)d_in[6];
    const float* ob0    = (const float*)d_in[7];
    const float* ow1    = (const float*)d_in[8];
    const float* ob1    = (const float*)d_in[9];
    const float* ow2    = (const float*)d_in[10];
    const float* ob2    = (const float*)d_in[11];
    const float* ow3    = (const float*)d_in[12];
    const float* ob3    = (const float*)d_in[13];
    float* out = (float*)d_out;

    char* wsb = (char*)d_ws;
    short* xpad1 = (short*)wsb;   wsb += (size_t)4 * PHW * 224 * 2;
    short* hpa   = (short*)wsb;   wsb += (size_t)4 * PHW * 64 * 2;
    short* hpb   = (short*)wsb;   wsb += (size_t)4 * PHW * 64 * 2;
    float* offpair = (float*)wsb; wsb += (size_t)4 * 144 * HW * 2 * 4;
    short* maskbuf = (short*)wsb; wsb += (size_t)4 * 144 * HW * 2;
    short* xdp     = (short*)wsb; wsb += (size_t)4 * 16 * QSLOTS * 32 * 2 + 64;
    short* wb0     = (short*)wsb; wsb += 64 * 9 * 224 * 2;
    short* wb1     = (short*)wsb; wsb += 64 * 9 * 64 * 2;
    short* wb2     = (short*)wsb; wsb += 64 * 9 * 64 * 2;
    short* wb3     = (short*)wsb; wsb += 448 * 9 * 64 * 2;
    short* wbd     = (short*)wsb;

    // prep_misc elements: borders 546304 + xdp border slots 148224 + weights 534528
    const int prep_total = 546304 + 148224 + 534528;
    prep_misc<<<dim3((prep_total + 255) / 256), 256, 0, stream>>>(
        xpad1, hpa, hpb, xdp, ow0, ow1, ow2, ow3, weight,
        wb0, wb1, wb2, wb3, wbd);
    pack_all<<<dim3(288, 11, 4), 256, 0, stream>>>(extra, flow1, flow2, x, xpad1, xdp);

    conv_mfma<224, 7><<<dim3(144, 4), 256, 0, stream>>>(xpad1, wb0, ob0, hpa);
    conv_mfma<64, 2><<<dim3(144, 4), 256, 0, stream>>>(hpa, wb1, ob1, hpb);
    conv_mfma<64, 2><<<dim3(144, 4), 256, 0, stream>>>(hpb, wb2, ob2, hpa);
    conv4_mfma<<<dim3(144, 4, 7), 256, 0, stream>>>(hpa, wb3, ob3, offpair,
                                                    maskbuf, flow1, flow2);
    deform_mfma<<<dim3(2304), 256, 0, stream>>>(xdp, offpair, maskbuf, wbd, bias, out);
}

// Round 4
// 299.511 us; speedup vs baseline: 1.0873x; 1.0873x over previous
//
#include <hip/hip_runtime.h>
#include <math.h>

#define HW 9216
#define Hh 96
#define Ww 96
#define PHW 9604   // 98*98 padded

typedef __attribute__((ext_vector_type(8))) short bh8;
typedef __attribute__((ext_vector_type(4))) short bh4;
typedef __attribute__((ext_vector_type(4))) float f32x4;
typedef __attribute__((ext_vector_type(2))) float f32x2;
typedef __attribute__((ext_vector_type(4))) int i32x4;
union bh8i { bh8 v; i32x4 i; };

__device__ __forceinline__ short f2bf(float f) {
    union { float f; unsigned u; } v; v.f = f;
    unsigned r = v.u + 0x7FFFu + ((v.u >> 16) & 1u);
    return (short)(r >> 16);
}
__device__ __forceinline__ float bf2f(short s) {
    union { unsigned u; float f; } v; v.u = ((unsigned)(unsigned short)s) << 16;
    return v.f;
}
__device__ __forceinline__ float lo_bf(unsigned u) {
    union { unsigned u; float f; } v; v.u = u << 16; return v.f;
}
__device__ __forceinline__ float hi_bf(unsigned u) {
    union { unsigned u; float f; } v; v.u = u & 0xFFFF0000u; return v.f;
}
// packed RNE f32->bf16x2 (identical rounding to f2bf), 1 instr
__device__ __forceinline__ int cvt_pk_bf16(float lo, float hi) {
    int r;
    asm("v_cvt_pk_bf16_f32 %0, %1, %2" : "=v"(r) : "v"(lo), "v"(hi));
    return r;
}

// ---------------------------------------------------------------------------
// Fused misc prep: pad-border zeroing (xpad1/hpa/hpb/xdp) + all weight prep.
__global__ void prep_misc(short* __restrict__ xpad1, short* __restrict__ hpa,
                          short* __restrict__ hpb, short* __restrict__ xdp,
                          const float* __restrict__ ow0, const float* __restrict__ ow1,
                          const float* __restrict__ ow2, const float* __restrict__ ow3,
                          const float* __restrict__ wd,
                          short* __restrict__ wb0, short* __restrict__ wb1,
                          short* __restrict__ wb2, short* __restrict__ wb3,
                          short* __restrict__ wbd) {
    int i = blockIdx.x * 256 + threadIdx.x;
    const int z1 = 4 * 388 * 224, z2 = 4 * 388 * 64;
    // --- segment A: borders of xpad1/hpa/hpb
    if (i < z1 + 2 * z2) {
        short* p; int C;
        if (i < z1) { p = xpad1; C = 224; }
        else if (i < z1 + z2) { p = hpa; C = 64; i -= z1; }
        else { p = hpb; C = 64; i -= z1 + z2; }
        int c = i % C;
        int r = i / C;
        int b = r / 388, pid = r - b * 388;
        int row, col;
        if (pid < 98)       { row = 0;  col = pid; }
        else if (pid < 196) { row = 97; col = pid - 98; }
        else if (pid < 292) { row = pid - 196 + 1; col = 0; }
        else                { row = pid - 292 + 1; col = 97; }
        p[((size_t)b * PHW + row * 98 + col) * C + c] = 0;
        return;
    }
    i -= z1 + 2 * z2;
    // --- segment B: ring of xdp (per b,g)
    const int zr = 4 * 16 * 388 * 8;
    if (i < zr) {
        int c8 = i & 7;
        int r = i >> 3;
        int pid = r % 388;
        int bg = r / 388;
        int row, col;
        if (pid < 98)       { row = 0;  col = pid; }
        else if (pid < 196) { row = 97; col = pid - 98; }
        else if (pid < 292) { row = pid - 196 + 1; col = 0; }
        else                { row = pid - 292 + 1; col = 97; }
        xdp[((size_t)bg * PHW + row * 98 + col) * 8 + c8] = 0;
        return;
    }
    i -= zr;
    // --- segment C: weights
    const int n0 = 64 * 9 * 224, n1 = 64 * 9 * 64, n3 = 448 * 9 * 64, nd = 64 * 1152;
    if (i < n0) {
        int co = i / (9 * 224); int r = i - co * (9 * 224);
        int tap = r / 224, ci = r - tap * 224;
        wb0[i] = f2bf(ci < 196 ? ow0[(co * 196 + ci) * 9 + tap] : 0.f);
        return;
    }
    i -= n0;
    if (i < n1) {
        int co = i / (9 * 64); int r = i - co * (9 * 64);
        int tap = r / 64, ci = r - tap * 64;
        wb1[i] = f2bf(ow1[(co * 64 + ci) * 9 + tap]);
        return;
    }
    i -= n1;
    if (i < n1) {
        int co = i / (9 * 64); int r = i - co * (9 * 64);
        int tap = r / 64, ci = r - tap * 64;
        wb2[i] = f2bf(ow2[(co * 64 + ci) * 9 + tap]);
        return;
    }
    i -= n1;
    if (i < n3) {
        int co = i / (9 * 64); int r = i - co * (9 * 64);
        int tap = r / 64, ci = r - tap * 64;
        wb3[i] = f2bf(co < 432 ? ow3[(co * 64 + ci) * 9 + tap] : 0.f);
        return;
    }
    i -= n3;
    if (i < nd) {
        int co = i / 1152, kd = i - co * 1152;
        int gt = kd >> 3, c = kd & 7;
        int g = gt / 9, tap = gt - g * 9;
        wbd[i] = f2bf(wd[(co * 128 + g * 8 + c) * 9 + tap]);
    }
}

// ---------------------------------------------------------------------------
// Fused packers. y<7: concat->xpad1 (ct=y). y>=7: x->xdp padded group-planar.
__global__ void pack_all(const float* __restrict__ extra,
                         const float* __restrict__ f1,
                         const float* __restrict__ f2,
                         const float* __restrict__ x,
                         short* __restrict__ xp,
                         short* __restrict__ xdp) {
    __shared__ float t[32][33];
    const int tid = threadIdx.x, tx = tid & 31, ty = tid >> 5;
    const int pt = blockIdx.x, b = blockIdx.z;
    if (blockIdx.y < 7) {
        const int ct = blockIdx.y;
#pragma unroll
        for (int j = 0; j < 4; ++j) {
            int ch = ct * 32 + ty + j * 8;
            int p = pt * 32 + tx;
            float v = 0.f;
            if (ch < 192)      v = extra[(b * 192 + ch) * HW + p];
            else if (ch < 194) v = f1[(b * 2 + ch - 192) * HW + p];
            else if (ch < 196) v = f2[(b * 2 + ch - 194) * HW + p];
            t[ty + j * 8][tx] = v;
        }
        __syncthreads();
#pragma unroll
        for (int j = 0; j < 4; ++j) {
            int pr = ty + j * 8;
            int p = pt * 32 + pr;
            int r = p / 96, c = p - r * 96;
            xp[((size_t)b * PHW + (r + 1) * 98 + (c + 1)) * 224 + ct * 32 + tx] =
                f2bf(t[tx][pr]);
        }
    } else {
        const int ct = blockIdx.y - 7;
#pragma unroll
        for (int j = 0; j < 4; ++j) {
            int ch = ct * 32 + ty + j * 8;
            t[ty + j * 8][tx] = x[((size_t)b * 128 + ch) * HW + pt * 32 + tx];
        }
        __syncthreads();
        if (tid < 128) {
            int oct = tid >> 5, p = tid & 31;
            int g = ct * 4 + oct;
            int pix = pt * 32 + p;
            int r = pix / 96, c = pix - r * 96;
            bh8 v;
#pragma unroll
            for (int cc = 0; cc < 8; ++cc) v[cc] = f2bf(t[oct * 8 + cc][p]);
            *(bh8*)&xdp[(((size_t)b * 16 + g) * PHW + (r + 1) * 98 + (c + 1)) * 8] = v;
        }
    }
}

// ---------------------------------------------------------------------------
// conv1-3 (round-6 structure): block = 4 waves x (16px x 64co), weight chunk
// staged in LDS per 32-cin chunk, B-frags direct 16B global loads.
// ---------------------------------------------------------------------------
template<int CINP, int KCH>
__launch_bounds__(256)
__global__ void conv_mfma(const short* __restrict__ xp,
                          const short* __restrict__ wb,
                          const float* __restrict__ bias,
                          short* __restrict__ o1) {
    __shared__ __attribute__((aligned(16))) short smA[9 * 64 * 32];
    const int tid = threadIdx.x;
    const int lane = tid & 63, wv = tid >> 6;
    const int q = lane >> 4, l15 = lane & 15;
    const int b = blockIdx.y;
    const int pix0 = blockIdx.x * 64 + wv * 16;
    const int soh = pix0 / 96, sow = pix0 - (pix0 / 96) * 96;

    const short* bp = xp + ((size_t)b * PHW + soh * 98 + sow + l15) * CINP + q * 8;

    const int sco = tid >> 2, sqq = tid & 3;
    const short* wsrc = wb + (size_t)sco * (9 * CINP) + sqq * 8;

    f32x4 acc[4];
#pragma unroll
    for (int t = 0; t < 4; ++t) acc[t] = (f32x4){0.f, 0.f, 0.f, 0.f};

    for (int p = 0; p < KCH; ++p) {
        __syncthreads();
        bh8 wtmp[9];
#pragma unroll
        for (int tap = 0; tap < 9; ++tap)
            wtmp[tap] = *(const bh8*)(wsrc + tap * CINP + p * 32);
#pragma unroll
        for (int tap = 0; tap < 9; ++tap)
            *(bh8*)&smA[tap * 2048 + sco * 32 + sqq * 8] = wtmp[tap];
        __syncthreads();
#pragma unroll
        for (int tap = 0; tap < 9; ++tap) {
            const int ky = tap / 3, kx = tap - (tap / 3) * 3;
            bh8 bf = *(const bh8*)(bp + (ky * 98 + kx) * CINP + p * 32);
#pragma unroll
            for (int t = 0; t < 4; ++t) {
                bh8 af = *(const bh8*)&smA[tap * 2048 + (t * 16 + l15) * 32 + q * 8];
                acc[t] = __builtin_amdgcn_mfma_f32_16x16x32_bf16(af, bf, acc[t], 0, 0, 0);
            }
        }
    }

    size_t base = ((size_t)b * PHW + (soh + 1) * 98 + sow + l15 + 1) * 64;
#pragma unroll
    for (int t = 0; t < 4; ++t) {
        bh4 v4;
#pragma unroll
        for (int r = 0; r < 4; ++r) {
            int co = t * 16 + q * 4 + r;
            float v = acc[t][r] + bias[co];
            v = (v >= 0.f) ? v : 0.1f * v;
            v4[r] = f2bf(v);
        }
        *(bh4*)(o1 + base + t * 16 + q * 4) = v4;
    }
}

// ---------------------------------------------------------------------------
// conv4 in the conv_mfma structure: grid (144,4,7), bz = 64-co block. Weights
// LDS-staged once per 32-ch chunk (4 barriers/block vs 18 in the old tiled
// GEMM), activations loaded per-lane direct from global (hpa is L3-resident).
// Epilogue: offset channels -> 10*tanh + flow, f32x2 pair store; mask
// channels -> sigmoid -> bf16.
// ---------------------------------------------------------------------------
__launch_bounds__(256)
__global__ void conv4_mfma(const short* __restrict__ xp,
                           const short* __restrict__ wb,   // wb3: [co][tap][64]
                           const float* __restrict__ bias,
                           float* __restrict__ offp,
                           short* __restrict__ maskb,
                           const float* __restrict__ flow1,
                           const float* __restrict__ flow2) {
    __shared__ __attribute__((aligned(16))) short smA[9 * 64 * 32];
    const int tid = threadIdx.x;
    const int lane = tid & 63, wv = tid >> 6;
    const int q = lane >> 4, l15 = lane & 15;
    const int b = blockIdx.y;
    const int cob = blockIdx.z * 64;
    const int pix0 = blockIdx.x * 64 + wv * 16;
    const int soh = pix0 / 96, sow = pix0 - (pix0 / 96) * 96;

    const short* bp = xp + ((size_t)b * PHW + soh * 98 + sow + l15) * 64 + q * 8;

    const int sco = tid >> 2, sqq = tid & 3;
    const short* wsrc = wb + (size_t)(cob + sco) * 576 + sqq * 8;

    f32x4 acc[4];
#pragma unroll
    for (int t = 0; t < 4; ++t) acc[t] = (f32x4){0.f, 0.f, 0.f, 0.f};

    for (int p = 0; p < 2; ++p) {
        __syncthreads();
        bh8 wtmp[9];
#pragma unroll
        for (int tap = 0; tap < 9; ++tap)
            wtmp[tap] = *(const bh8*)(wsrc + tap * 64 + p * 32);
#pragma unroll
        for (int tap = 0; tap < 9; ++tap)
            *(bh8*)&smA[tap * 2048 + sco * 32 + sqq * 8] = wtmp[tap];
        __syncthreads();
#pragma unroll
        for (int tap = 0; tap < 9; ++tap) {
            const int ky = tap / 3, kx = tap - (tap / 3) * 3;
            bh8 bf = *(const bh8*)(bp + (ky * 98 + kx) * 64 + p * 32);
#pragma unroll
            for (int t = 0; t < 4; ++t) {
                bh8 af = *(const bh8*)&smA[tap * 2048 + (t * 16 + l15) * 32 + q * 8];
                acc[t] = __builtin_amdgcn_mfma_f32_16x16x32_bf16(af, bf, acc[t], 0, 0, 0);
            }
        }
    }

    const int pix = pix0 + l15;
#pragma unroll
    for (int t = 0; t < 4; ++t) {
        int cb0 = cob + t * 16 + q * 4;
        if (cb0 < 288) {
            const float* fl = (cb0 < 144) ? flow1 : flow2;
            float fe = fl[(b * 2 + 1) * HW + pix];
            float fo = fl[(b * 2) * HW + pix];
            float t0 = 10.f * tanhf(acc[t][0] + bias[cb0 + 0]) + fe;
            float t1 = 10.f * tanhf(acc[t][1] + bias[cb0 + 1]) + fo;
            float t2 = 10.f * tanhf(acc[t][2] + bias[cb0 + 2]) + fe;
            float t3 = 10.f * tanhf(acc[t][3] + bias[cb0 + 3]) + fo;
            size_t p0 = ((size_t)b * 144 + (cb0 >> 1)) * HW + pix;
            *(f32x2*)&offp[p0 * 2] = (f32x2){t0, t1};
            *(f32x2*)&offp[(p0 + HW) * 2] = (f32x2){t2, t3};
        } else {
#pragma unroll
            for (int r = 0; r < 4; ++r) {
                int chn = cb0 + r;
                if (chn < 432) {
                    float v = acc[t][r] + bias[chn];
                    maskb[((size_t)b * 144 + (chn - 288)) * HW + pix] =
                        f2bf(1.f / (1.f + expf(-v)));
                }
            }
        }
    }
}

// ---------------------------------------------------------------------------
// Deform (round-0 structure): padded zero-ring xdp (no masks/bounds: clamp
// coords to [-1,96]), all 9 pointers+weights precomputed so loads can be
// hoisted deep; packed f32x2 bilinear + v_cvt_pk_bf16_f32 repack.
// XCD-swizzled blocks.
// ---------------------------------------------------------------------------
__launch_bounds__(256)
__global__ void deform_mfma(const short* __restrict__ xdp,
                            const float* __restrict__ offp,
                            const short* __restrict__ maskb,
                            const short* __restrict__ wbd,
                            const float* __restrict__ bias,
                            float* __restrict__ out) {
    __shared__ float red[4][1024];
    const int tid = threadIdx.x;
    const int lane = tid & 63, wv = tid >> 6;
    const int q = lane >> 4, l15 = lane & 15;
    const int blk = blockIdx.x;
    const int xs = blk & 7, idx = blk >> 3;
    const int b = xs >> 1;
    const int pix0 = ((xs & 1) * 288 + idx) * 16;
    const int pix = pix0 + l15;
    const int h = pix / 96, w = pix - (pix / 96) * 96;

    const float* opp = offp + ((size_t)b * 144 * HW + pix) * 2;
    const short* mp = maskb + (size_t)b * 144 * HW + pix;
    const short* xb = xdp + (size_t)b * 16 * PHW * 8;
    const short* ap = wbd + (size_t)l15 * 1152 + wv * 288 + q * 8;

    f32x2 dxy[9];
    float mk[9];
#pragma unroll
    for (int i = 0; i < 9; ++i) {
        const int gt = wv * 36 + i * 4 + q;
        dxy[i] = *(const f32x2*)(opp + (size_t)gt * HW * 2);
        mk[i] = bf2f(mp[(size_t)gt * HW]);
    }

    // precompute pointers + weights for all 9 samples
    const short* cp[9];
    f32x4 ww[9];
#pragma unroll
    for (int i = 0; i < 9; ++i) {
        const int gt = wv * 36 + i * 4 + q;
        const int g = gt / 9, tap = gt - (gt / 9) * 9;
        float py = dxy[i][0] + (float)(tap / 3) + (float)h - 1.f;
        float px = dxy[i][1] + (float)(tap - (tap / 3) * 3) + (float)w - 1.f;
        py = fminf(fmaxf(py, -1.f), 96.f);
        px = fminf(fmaxf(px, -1.f), 96.f);
        float y0f = floorf(py), x0f = floorf(px);
        float wy1 = py - y0f, wx1 = px - x0f;
        float wy0 = 1.f - wy1, wx0 = 1.f - wx1;
        int yp = (int)y0f + 1, xp = (int)x0f + 1;
        cp[i] = xb + ((size_t)g * PHW + yp * 98 + xp) * 8;
        float m = mk[i];
        ww[i] = (f32x4){wy0 * wx0 * m, wy0 * wx1 * m, wy1 * wx0 * m, wy1 * wx1 * m};
    }

    f32x4 acc[4];
#pragma unroll
    for (int t = 0; t < 4; ++t) acc[t] = (f32x4){0.f, 0.f, 0.f, 0.f};

#pragma unroll
    for (int i = 0; i < 9; ++i) {
        bh8i c00, c01, c10, c11;
        c00.v = *(const bh8*)(cp[i]);
        c01.v = *(const bh8*)(cp[i] + 8);
        c10.v = *(const bh8*)(cp[i] + 98 * 8);
        c11.v = *(const bh8*)(cp[i] + 99 * 8);
        const f32x2 W00 = (f32x2){ww[i][0], ww[i][0]};
        const f32x2 W01 = (f32x2){ww[i][1], ww[i][1]};
        const f32x2 W10 = (f32x2){ww[i][2], ww[i][2]};
        const f32x2 W11 = (f32x2){ww[i][3], ww[i][3]};
        bh8i bf;
#pragma unroll
        for (int k = 0; k < 4; ++k) {
            unsigned u00 = (unsigned)c00.i[k], u01 = (unsigned)c01.i[k];
            unsigned u10 = (unsigned)c10.i[k], u11 = (unsigned)c11.i[k];
            f32x2 p00 = (f32x2){lo_bf(u00), hi_bf(u00)};
            f32x2 p01 = (f32x2){lo_bf(u01), hi_bf(u01)};
            f32x2 p10 = (f32x2){lo_bf(u10), hi_bf(u10)};
            f32x2 p11 = (f32x2){lo_bf(u11), hi_bf(u11)};
            f32x2 s = p00 * W00 + p01 * W01 + p10 * W10 + p11 * W11;
            bf.i[k] = cvt_pk_bf16(s[0], s[1]);
        }
#pragma unroll
        for (int t = 0; t < 4; ++t) {
            bh8 af = *(const bh8*)(ap + (size_t)t * 16 * 1152 + i * 32);
            acc[t] = __builtin_amdgcn_mfma_f32_16x16x32_bf16(af, bf.v, acc[t], 0, 0, 0);
        }
    }

#pragma unroll
    for (int t = 0; t < 4; ++t)
#pragma unroll
        for (int r = 0; r < 4; ++r)
            red[wv][(t * 16 + q * 4 + r) * 16 + l15] = acc[t][r];
    __syncthreads();
    for (int e = tid; e < 1024; e += 256) {
        int co = e >> 4, pl = e & 15;
        float v = red[0][e] + red[1][e] + red[2][e] + red[3][e] + bias[co];
        out[((size_t)b * 64 + co) * HW + pix0 + pl] = v;
    }
}

// ---------------------------------------------------------------------------
extern "C" void kernel_launch(void* const* d_in, const int* in_sizes, int n_in,
                              void* d_out, int out_size, void* d_ws, size_t ws_size,
                              hipStream_t stream) {
    const float* x      = (const float*)d_in[0];
    const float* extra  = (const float*)d_in[1];
    const float* flow1  = (const float*)d_in[2];
    const float* flow2  = (const float*)d_in[3];
    const float* weight = (const float*)d_in[4];
    const float* bias   = (const float*)d_in[5];
    const float* ow0    = (const float*)d_in[6];
    const float* ob0    = (const float*)d_in[7];
    const float* ow1    = (const float*)d_in[8];
    const float* ob1    = (const float*)d_in[9];
    const float* ow2    = (const float*)d_in[10];
    const float* ob2    = (const float*)d_in[11];
    const float* ow3    = (const float*)d_in[12];
    const float* ob3    = (const float*)d_in[13];
    float* out = (float*)d_out;

    char* wsb = (char*)d_ws;
    short* xpad1 = (short*)wsb;   wsb += (size_t)4 * PHW * 224 * 2;
    short* hpa   = (short*)wsb;   wsb += (size_t)4 * PHW * 64 * 2;
    short* hpb   = (short*)wsb;   wsb += (size_t)4 * PHW * 64 * 2;
    float* offpair = (float*)wsb; wsb += (size_t)4 * 144 * HW * 2 * 4;
    short* maskbuf = (short*)wsb; wsb += (size_t)4 * 144 * HW * 2;
    short* xdp     = (short*)wsb; wsb += (size_t)4 * 16 * PHW * 8 * 2 + 32;
    short* wb0     = (short*)wsb; wsb += 64 * 9 * 224 * 2;
    short* wb1     = (short*)wsb; wsb += 64 * 9 * 64 * 2;
    short* wb2     = (short*)wsb; wsb += 64 * 9 * 64 * 2;
    short* wb3     = (short*)wsb; wsb += 448 * 9 * 64 * 2;
    short* wbd     = (short*)wsb;

    // prep_misc total elements: borders 546304 + xdp ring 198656 + weights 534528
    const int prep_total = 546304 + 198656 + 534528;
    prep_misc<<<dim3((prep_total + 255) / 256), 256, 0, stream>>>(
        xpad1, hpa, hpb, xdp, ow0, ow1, ow2, ow3, weight,
        wb0, wb1, wb2, wb3, wbd);
    pack_all<<<dim3(288, 11, 4), 256, 0, stream>>>(extra, flow1, flow2, x, xpad1, xdp);

    conv_mfma<224, 7><<<dim3(144, 4), 256, 0, stream>>>(xpad1, wb0, ob0, hpa);
    conv_mfma<64, 2><<<dim3(144, 4), 256, 0, stream>>>(hpa, wb1, ob1, hpb);
    conv_mfma<64, 2><<<dim3(144, 4), 256, 0, stream>>>(hpb, wb2, ob2, hpa);
    conv4_mfma<<<dim3(144, 4, 7), 256, 0, stream>>>(hpa, wb3, ob3, offpair,
                                                    maskbuf, flow1, flow2);
    deform_mfma<<<dim3(2304), 256, 0, stream>>>(xdp, offpair, maskbuf, wbd, bias, out);
}

// Round 5
// 282.424 us; speedup vs baseline: 1.1531x; 1.0605x over previous
//
#include <hip/hip_runtime.h>
#include <math.h>

#define HW 9216
#define Hh 96
#define Ww 96
#define PHW 9604   // 98*98 padded

typedef __attribute__((ext_vector_type(8))) short bh8;
typedef __attribute__((ext_vector_type(4))) short bh4;
typedef __attribute__((ext_vector_type(4))) float f32x4;
typedef __attribute__((ext_vector_type(2))) float f32x2;
typedef __attribute__((ext_vector_type(4))) int i32x4;
union bh8i { bh8 v; i32x4 i; };

__device__ __forceinline__ short f2bf(float f) {
    union { float f; unsigned u; } v; v.f = f;
    unsigned r = v.u + 0x7FFFu + ((v.u >> 16) & 1u);
    return (short)(r >> 16);
}
__device__ __forceinline__ float bf2f(short s) {
    union { unsigned u; float f; } v; v.u = ((unsigned)(unsigned short)s) << 16;
    return v.f;
}
__device__ __forceinline__ float lo_bf(unsigned u) {
    union { unsigned u; float f; } v; v.u = u << 16; return v.f;
}
__device__ __forceinline__ float hi_bf(unsigned u) {
    union { unsigned u; float f; } v; v.u = u & 0xFFFF0000u; return v.f;
}
// packed RNE f32->bf16x2 (identical rounding to f2bf), 1 instr
__device__ __forceinline__ int cvt_pk_bf16(float lo, float hi) {
    int r;
    asm("v_cvt_pk_bf16_f32 %0, %1, %2" : "=v"(r) : "v"(lo), "v"(hi));
    return r;
}

// ---------------------------------------------------------------------------
// Fused misc prep: pad-border zeroing (xpad1/hpa/hpb/xdp) + all weight prep.
__global__ void prep_misc(short* __restrict__ xpad1, short* __restrict__ hpa,
                          short* __restrict__ hpb, short* __restrict__ xdp,
                          const float* __restrict__ ow0, const float* __restrict__ ow1,
                          const float* __restrict__ ow2, const float* __restrict__ ow3,
                          const float* __restrict__ wd,
                          short* __restrict__ wb0, short* __restrict__ wb1,
                          short* __restrict__ wb2, short* __restrict__ wb3,
                          short* __restrict__ wbd) {
    int i = blockIdx.x * 256 + threadIdx.x;
    const int z1 = 4 * 388 * 224, z2 = 4 * 388 * 64;
    // --- segment A: borders of xpad1/hpa/hpb
    if (i < z1 + 2 * z2) {
        short* p; int C;
        if (i < z1) { p = xpad1; C = 224; }
        else if (i < z1 + z2) { p = hpa; C = 64; i -= z1; }
        else { p = hpb; C = 64; i -= z1 + z2; }
        int c = i % C;
        int r = i / C;
        int b = r / 388, pid = r - b * 388;
        int row, col;
        if (pid < 98)       { row = 0;  col = pid; }
        else if (pid < 196) { row = 97; col = pid - 98; }
        else if (pid < 292) { row = pid - 196 + 1; col = 0; }
        else                { row = pid - 292 + 1; col = 97; }
        p[((size_t)b * PHW + row * 98 + col) * C + c] = 0;
        return;
    }
    i -= z1 + 2 * z2;
    // --- segment B: ring of xdp (per b,g)
    const int zr = 4 * 16 * 388 * 8;
    if (i < zr) {
        int c8 = i & 7;
        int r = i >> 3;
        int pid = r % 388;
        int bg = r / 388;
        int row, col;
        if (pid < 98)       { row = 0;  col = pid; }
        else if (pid < 196) { row = 97; col = pid - 98; }
        else if (pid < 292) { row = pid - 196 + 1; col = 0; }
        else                { row = pid - 292 + 1; col = 97; }
        xdp[((size_t)bg * PHW + row * 98 + col) * 8 + c8] = 0;
        return;
    }
    i -= zr;
    // --- segment C: weights
    const int n0 = 64 * 9 * 224, n1 = 64 * 9 * 64, n3 = 448 * 9 * 64, nd = 64 * 1152;
    if (i < n0) {
        int co = i / (9 * 224); int r = i - co * (9 * 224);
        int tap = r / 224, ci = r - tap * 224;
        wb0[i] = f2bf(ci < 196 ? ow0[(co * 196 + ci) * 9 + tap] : 0.f);
        return;
    }
    i -= n0;
    if (i < n1) {
        int co = i / (9 * 64); int r = i - co * (9 * 64);
        int tap = r / 64, ci = r - tap * 64;
        wb1[i] = f2bf(ow1[(co * 64 + ci) * 9 + tap]);
        return;
    }
    i -= n1;
    if (i < n1) {
        int co = i / (9 * 64); int r = i - co * (9 * 64);
        int tap = r / 64, ci = r - tap * 64;
        wb2[i] = f2bf(ow2[(co * 64 + ci) * 9 + tap]);
        return;
    }
    i -= n1;
    if (i < n3) {
        int co = i / (9 * 64); int r = i - co * (9 * 64);
        int tap = r / 64, ci = r - tap * 64;
        wb3[i] = f2bf(co < 432 ? ow3[(co * 64 + ci) * 9 + tap] : 0.f);
        return;
    }
    i -= n3;
    if (i < nd) {
        // deform weight slab layout: [slab(36)][co(64)][k(32)]
        // slab = gt>>2, k = (gt&3)*8 + c8
        int slab = i >> 11, r = i & 2047;
        int co = r >> 5, k = r & 31;
        int gt = slab * 4 + (k >> 3), c8 = k & 7;
        int g = gt / 9, tap = gt - g * 9;
        wbd[i] = f2bf(wd[(co * 128 + g * 8 + c8) * 9 + tap]);
    }
}

// ---------------------------------------------------------------------------
// Fused packers. y<7: concat->xpad1 (ct=y). y>=7: x->xdp padded group-planar.
__global__ void pack_all(const float* __restrict__ extra,
                         const float* __restrict__ f1,
                         const float* __restrict__ f2,
                         const float* __restrict__ x,
                         short* __restrict__ xp,
                         short* __restrict__ xdp) {
    __shared__ float t[32][33];
    const int tid = threadIdx.x, tx = tid & 31, ty = tid >> 5;
    const int pt = blockIdx.x, b = blockIdx.z;
    if (blockIdx.y < 7) {
        const int ct = blockIdx.y;
#pragma unroll
        for (int j = 0; j < 4; ++j) {
            int ch = ct * 32 + ty + j * 8;
            int p = pt * 32 + tx;
            float v = 0.f;
            if (ch < 192)      v = extra[(b * 192 + ch) * HW + p];
            else if (ch < 194) v = f1[(b * 2 + ch - 192) * HW + p];
            else if (ch < 196) v = f2[(b * 2 + ch - 194) * HW + p];
            t[ty + j * 8][tx] = v;
        }
        __syncthreads();
#pragma unroll
        for (int j = 0; j < 4; ++j) {
            int pr = ty + j * 8;
            int p = pt * 32 + pr;
            int r = p / 96, c = p - r * 96;
            xp[((size_t)b * PHW + (r + 1) * 98 + (c + 1)) * 224 + ct * 32 + tx] =
                f2bf(t[tx][pr]);
        }
    } else {
        const int ct = blockIdx.y - 7;
#pragma unroll
        for (int j = 0; j < 4; ++j) {
            int ch = ct * 32 + ty + j * 8;
            t[ty + j * 8][tx] = x[((size_t)b * 128 + ch) * HW + pt * 32 + tx];
        }
        __syncthreads();
        if (tid < 128) {
            int oct = tid >> 5, p = tid & 31;
            int g = ct * 4 + oct;
            int pix = pt * 32 + p;
            int r = pix / 96, c = pix - r * 96;
            bh8 v;
#pragma unroll
            for (int cc = 0; cc < 8; ++cc) v[cc] = f2bf(t[oct * 8 + cc][p]);
            *(bh8*)&xdp[(((size_t)b * 16 + g) * PHW + (r + 1) * 98 + (c + 1)) * 8] = v;
        }
    }
}

// ---------------------------------------------------------------------------
// conv1-3 (round-6 structure): block = 4 waves x (16px x 64co), weight chunk
// staged in LDS per 32-cin chunk, B-frags direct 16B global loads.
// ---------------------------------------------------------------------------
template<int CINP, int KCH>
__launch_bounds__(256)
__global__ void conv_mfma(const short* __restrict__ xp,
                          const short* __restrict__ wb,
                          const float* __restrict__ bias,
                          short* __restrict__ o1) {
    __shared__ __attribute__((aligned(16))) short smA[9 * 64 * 32];
    const int tid = threadIdx.x;
    const int lane = tid & 63, wv = tid >> 6;
    const int q = lane >> 4, l15 = lane & 15;
    const int b = blockIdx.y;
    const int pix0 = blockIdx.x * 64 + wv * 16;
    const int soh = pix0 / 96, sow = pix0 - (pix0 / 96) * 96;

    const short* bp = xp + ((size_t)b * PHW + soh * 98 + sow + l15) * CINP + q * 8;

    const int sco = tid >> 2, sqq = tid & 3;
    const short* wsrc = wb + (size_t)sco * (9 * CINP) + sqq * 8;

    f32x4 acc[4];
#pragma unroll
    for (int t = 0; t < 4; ++t) acc[t] = (f32x4){0.f, 0.f, 0.f, 0.f};

    for (int p = 0; p < KCH; ++p) {
        __syncthreads();
        bh8 wtmp[9];
#pragma unroll
        for (int tap = 0; tap < 9; ++tap)
            wtmp[tap] = *(const bh8*)(wsrc + tap * CINP + p * 32);
#pragma unroll
        for (int tap = 0; tap < 9; ++tap)
            *(bh8*)&smA[tap * 2048 + sco * 32 + sqq * 8] = wtmp[tap];
        __syncthreads();
#pragma unroll
        for (int tap = 0; tap < 9; ++tap) {
            const int ky = tap / 3, kx = tap - (tap / 3) * 3;
            bh8 bf = *(const bh8*)(bp + (ky * 98 + kx) * CINP + p * 32);
#pragma unroll
            for (int t = 0; t < 4; ++t) {
                bh8 af = *(const bh8*)&smA[tap * 2048 + (t * 16 + l15) * 32 + q * 8];
                acc[t] = __builtin_amdgcn_mfma_f32_16x16x32_bf16(af, bf, acc[t], 0, 0, 0);
            }
        }
    }

    size_t base = ((size_t)b * PHW + (soh + 1) * 98 + sow + l15 + 1) * 64;
#pragma unroll
    for (int t = 0; t < 4; ++t) {
        bh4 v4;
#pragma unroll
        for (int r = 0; r < 4; ++r) {
            int co = t * 16 + q * 4 + r;
            float v = acc[t][r] + bias[co];
            v = (v >= 0.f) ? v : 0.1f * v;
            v4[r] = f2bf(v);
        }
        *(bh4*)(o1 + base + t * 16 + q * 4) = v4;
    }
}

// ---------------------------------------------------------------------------
// conv4 in the conv_mfma structure: grid (144,4,7), bz = 64-co block.
// ---------------------------------------------------------------------------
__launch_bounds__(256)
__global__ void conv4_mfma(const short* __restrict__ xp,
                           const short* __restrict__ wb,   // wb3: [co][tap][64]
                           const float* __restrict__ bias,
                           float* __restrict__ offp,
                           short* __restrict__ maskb,
                           const float* __restrict__ flow1,
                           const float* __restrict__ flow2) {
    __shared__ __attribute__((aligned(16))) short smA[9 * 64 * 32];
    const int tid = threadIdx.x;
    const int lane = tid & 63, wv = tid >> 6;
    const int q = lane >> 4, l15 = lane & 15;
    const int b = blockIdx.y;
    const int cob = blockIdx.z * 64;
    const int pix0 = blockIdx.x * 64 + wv * 16;
    const int soh = pix0 / 96, sow = pix0 - (pix0 / 96) * 96;

    const short* bp = xp + ((size_t)b * PHW + soh * 98 + sow + l15) * 64 + q * 8;

    const int sco = tid >> 2, sqq = tid & 3;
    const short* wsrc = wb + (size_t)(cob + sco) * 576 + sqq * 8;

    f32x4 acc[4];
#pragma unroll
    for (int t = 0; t < 4; ++t) acc[t] = (f32x4){0.f, 0.f, 0.f, 0.f};

    for (int p = 0; p < 2; ++p) {
        __syncthreads();
        bh8 wtmp[9];
#pragma unroll
        for (int tap = 0; tap < 9; ++tap)
            wtmp[tap] = *(const bh8*)(wsrc + tap * 64 + p * 32);
#pragma unroll
        for (int tap = 0; tap < 9; ++tap)
            *(bh8*)&smA[tap * 2048 + sco * 32 + sqq * 8] = wtmp[tap];
        __syncthreads();
#pragma unroll
        for (int tap = 0; tap < 9; ++tap) {
            const int ky = tap / 3, kx = tap - (tap / 3) * 3;
            bh8 bf = *(const bh8*)(bp + (ky * 98 + kx) * 64 + p * 32);
#pragma unroll
            for (int t = 0; t < 4; ++t) {
                bh8 af = *(const bh8*)&smA[tap * 2048 + (t * 16 + l15) * 32 + q * 8];
                acc[t] = __builtin_amdgcn_mfma_f32_16x16x32_bf16(af, bf, acc[t], 0, 0, 0);
            }
        }
    }

    const int pix = pix0 + l15;
#pragma unroll
    for (int t = 0; t < 4; ++t) {
        int cb0 = cob + t * 16 + q * 4;
        if (cb0 < 288) {
            const float* fl = (cb0 < 144) ? flow1 : flow2;
            float fe = fl[(b * 2 + 1) * HW + pix];
            float fo = fl[(b * 2) * HW + pix];
            float t0 = 10.f * tanhf(acc[t][0] + bias[cb0 + 0]) + fe;
            float t1 = 10.f * tanhf(acc[t][1] + bias[cb0 + 1]) + fo;
            float t2 = 10.f * tanhf(acc[t][2] + bias[cb0 + 2]) + fe;
            float t3 = 10.f * tanhf(acc[t][3] + bias[cb0 + 3]) + fo;
            size_t p0 = ((size_t)b * 144 + (cb0 >> 1)) * HW + pix;
            *(f32x2*)&offp[p0 * 2] = (f32x2){t0, t1};
            *(f32x2*)&offp[(p0 + HW) * 2] = (f32x2){t2, t3};
        } else {
#pragma unroll
            for (int r = 0; r < 4; ++r) {
                int chn = cb0 + r;
                if (chn < 432) {
                    float v = acc[t][r] + bias[chn];
                    maskb[((size_t)b * 144 + (chn - 288)) * HW + pix] =
                        f2bf(1.f / (1.f + expf(-v)));
                }
            }
        }
    }
}

// ---------------------------------------------------------------------------
// Deform v2: block = 4 waves x 16px = 64px, gt-HALF (72 gt = 18 K-chunks).
// wbd slabs LDS-staged 3 at a time (6 rounds, 2 barriers each) -> weight
// line-traffic amortized over 64 px instead of 16 (339MB -> 85MB). The two
// gt-halves accumulate into out via f32 atomicAdd (out pre-zeroed; IEEE add
// is commutative so result is deterministic). Offsets prefetched one round
// ahead; corner gathers 2-deep pipelined. No cross-wave reduction phase.
// ---------------------------------------------------------------------------
#define BLEND_MFMA(C0, C1, C2, C3, WWv, CL)                                    \
    {                                                                          \
        const f32x2 W00 = (f32x2){(WWv)[0], (WWv)[0]};                         \
        const f32x2 W01 = (f32x2){(WWv)[1], (WWv)[1]};                         \
        const f32x2 W10 = (f32x2){(WWv)[2], (WWv)[2]};                         \
        const f32x2 W11 = (f32x2){(WWv)[3], (WWv)[3]};                         \
        bh8i bf;                                                               \
        _Pragma("unroll")                                                      \
        for (int k = 0; k < 4; ++k) {                                          \
            unsigned u00 = (unsigned)(C0).i[k], u01 = (unsigned)(C1).i[k];     \
            unsigned u10 = (unsigned)(C2).i[k], u11 = (unsigned)(C3).i[k];     \
            f32x2 p00 = (f32x2){lo_bf(u00), hi_bf(u00)};                       \
            f32x2 p01 = (f32x2){lo_bf(u01), hi_bf(u01)};                       \
            f32x2 p10 = (f32x2){lo_bf(u10), hi_bf(u10)};                       \
            f32x2 p11 = (f32x2){lo_bf(u11), hi_bf(u11)};                       \
            f32x2 s = p00 * W00 + p01 * W01 + p10 * W10 + p11 * W11;           \
            bf.i[k] = cvt_pk_bf16(s[0], s[1]);                                 \
        }                                                                      \
        _Pragma("unroll")                                                      \
        for (int t = 0; t < 4; ++t) {                                          \
            bh8 af = *(const bh8*)&smW[(CL) * 2048 + (t * 16 + l15) * 32 + q * 8]; \
            acc[t] = __builtin_amdgcn_mfma_f32_16x16x32_bf16(af, bf.v, acc[t], 0, 0, 0); \
        }                                                                      \
    }

__launch_bounds__(256)
__global__ void deform_mfma(const short* __restrict__ xdp,
                            const float* __restrict__ offp,
                            const short* __restrict__ maskb,
                            const short* __restrict__ wbd,  // [36][64co][32k]
                            const float* __restrict__ bias,
                            float* __restrict__ out) {
    __shared__ __attribute__((aligned(16))) short smW[3 * 2048];
    const int tid = threadIdx.x;
    const int lane = tid & 63, wv = tid >> 6;
    const int q = lane >> 4, l15 = lane & 15;
    const int blk = blockIdx.x;
    const int xs = blk & 7, idx = blk >> 3;
    const int b = xs >> 1, gh = xs & 1;
    const int pixw = idx * 64 + wv * 16 + l15;
    const int h = pixw / 96, w = pixw - (pixw / 96) * 96;

    const float* opp = offp + ((size_t)(b * 144 + gh * 72) * HW + pixw) * 2;
    const short* mp  = maskb + (size_t)(b * 144 + gh * 72) * HW + pixw;
    const short* xb  = xdp + (size_t)b * 16 * PHW * 8;
    const short* wsrc = wbd + (size_t)(gh * 18) * 2048 + tid * 8;

    f32x4 acc[4];
#pragma unroll
    for (int t = 0; t < 4; ++t) acc[t] = (f32x4){0.f, 0.f, 0.f, 0.f};

    // prologue: round-0 offsets/masks
    f32x2 dc[3]; float mc[3];
#pragma unroll
    for (int cl = 0; cl < 3; ++cl) {
        int lt = cl * 4 + q;
        dc[cl] = *(const f32x2*)(opp + (size_t)lt * HW * 2);
        mc[cl] = bf2f(mp[(size_t)lt * HW]);
    }

    for (int r = 0; r < 6; ++r) {
        // stage 3 weight slabs (straight copy, coalesced both sides)
        __syncthreads();
        bh8 st0 = *(const bh8*)(wsrc + (r * 3 + 0) * 2048);
        bh8 st1 = *(const bh8*)(wsrc + (r * 3 + 1) * 2048);
        bh8 st2 = *(const bh8*)(wsrc + (r * 3 + 2) * 2048);
        *(bh8*)&smW[0 * 2048 + tid * 8] = st0;
        *(bh8*)&smW[1 * 2048 + tid * 8] = st1;
        *(bh8*)&smW[2 * 2048 + tid * 8] = st2;
        __syncthreads();

        // prefetch next round's offsets/masks (long-latency, hidden by MFMA)
        f32x2 dn[3]; float mn[3];
        if (r < 5) {
#pragma unroll
            for (int cl = 0; cl < 3; ++cl) {
                int lt = ((r + 1) * 3 + cl) * 4 + q;
                dn[cl] = *(const f32x2*)(opp + (size_t)lt * HW * 2);
                mn[cl] = bf2f(mp[(size_t)lt * HW]);
            }
        }

        // addresses + bilinear weights for this round's 3 chunks
        int soff[3]; f32x4 ww[3];
#pragma unroll
        for (int cl = 0; cl < 3; ++cl) {
            int gt = gh * 72 + (r * 3 + cl) * 4 + q;
            int g = gt / 9, tap = gt - g * 9;
            float py = dc[cl][0] + (float)(tap / 3) + (float)h - 1.f;
            float px = dc[cl][1] + (float)(tap - (tap / 3) * 3) + (float)w - 1.f;
            py = fminf(fmaxf(py, -1.f), 96.f);
            px = fminf(fmaxf(px, -1.f), 96.f);
            float y0f = floorf(py), x0f = floorf(px);
            float wy1 = py - y0f, wx1 = px - x0f;
            float wy0 = 1.f - wy1, wx0 = 1.f - wx1;
            int yp = (int)y0f + 1, xq = (int)x0f + 1;
            soff[cl] = (g * PHW + yp * 98 + xq) * 8;
            float m = mc[cl];
            ww[cl] = (f32x4){wy0 * wx0 * m, wy0 * wx1 * m, wy1 * wx0 * m, wy1 * wx1 * m};
        }

        // corner gathers, 2-deep pipeline (A: chunk0 then chunk2, B: chunk1)
        bh8i a0, a1, a2, a3, b0, b1, b2, b3;
        {
            const short* p = xb + soff[0];
            a0.v = *(const bh8*)(p);          a1.v = *(const bh8*)(p + 8);
            a2.v = *(const bh8*)(p + 98 * 8); a3.v = *(const bh8*)(p + 99 * 8);
        }
        {
            const short* p = xb + soff[1];
            b0.v = *(const bh8*)(p);          b1.v = *(const bh8*)(p + 8);
            b2.v = *(const bh8*)(p + 98 * 8); b3.v = *(const bh8*)(p + 99 * 8);
        }
        BLEND_MFMA(a0, a1, a2, a3, ww[0], 0);
        {
            const short* p = xb + soff[2];
            a0.v = *(const bh8*)(p);          a1.v = *(const bh8*)(p + 8);
            a2.v = *(const bh8*)(p + 98 * 8); a3.v = *(const bh8*)(p + 99 * 8);
        }
        BLEND_MFMA(b0, b1, b2, b3, ww[1], 1);
        BLEND_MFMA(a0, a1, a2, a3, ww[2], 2);

        if (r < 5) {
#pragma unroll
            for (int cl = 0; cl < 3; ++cl) { dc[cl] = dn[cl]; mc[cl] = mn[cl]; }
        }
    }

    // epilogue: accumulate this half into out (bias added once, by half 0)
#pragma unroll
    for (int t = 0; t < 4; ++t)
#pragma unroll
        for (int rr = 0; rr < 4; ++rr) {
            int co = t * 16 + q * 4 + rr;
            float v = acc[t][rr];
            if (gh == 0) v += bias[co];
            atomicAdd(&out[((size_t)b * 64 + co) * HW + pixw], v);
        }
}

// ---------------------------------------------------------------------------
extern "C" void kernel_launch(void* const* d_in, const int* in_sizes, int n_in,
                              void* d_out, int out_size, void* d_ws, size_t ws_size,
                              hipStream_t stream) {
    const float* x      = (const float*)d_in[0];
    const float* extra  = (const float*)d_in[1];
    const float* flow1  = (const float*)d_in[2];
    const float* flow2  = (const float*)d_in[3];
    const float* weight = (const float*)d_in[4];
    const float* bias   = (const float*)d_in[5];
    const float* ow0    = (const float*)d_in[6];
    const float* ob0    = (const float*)d_in[7];
    const float* ow1    = (const float*)d_in[8];
    const float* ob1    = (const float*)d_in[9];
    const float* ow2    = (const float*)d_in[10];
    const float* ob2    = (const float*)d_in[11];
    const float* ow3    = (const float*)d_in[12];
    const float* ob3    = (const float*)d_in[13];
    float* out = (float*)d_out;

    char* wsb = (char*)d_ws;
    short* xpad1 = (short*)wsb;   wsb += (size_t)4 * PHW * 224 * 2;
    short* hpa   = (short*)wsb;   wsb += (size_t)4 * PHW * 64 * 2;
    short* hpb   = (short*)wsb;   wsb += (size_t)4 * PHW * 64 * 2;
    float* offpair = (float*)wsb; wsb += (size_t)4 * 144 * HW * 2 * 4;
    short* maskbuf = (short*)wsb; wsb += (size_t)4 * 144 * HW * 2;
    short* xdp     = (short*)wsb; wsb += (size_t)4 * 16 * PHW * 8 * 2 + 32;
    short* wb0     = (short*)wsb; wsb += 64 * 9 * 224 * 2;
    short* wb1     = (short*)wsb; wsb += 64 * 9 * 64 * 2;
    short* wb2     = (short*)wsb; wsb += 64 * 9 * 64 * 2;
    short* wb3     = (short*)wsb; wsb += 448 * 9 * 64 * 2;
    short* wbd     = (short*)wsb;

    // out is accumulated into by the two gt-half deform passes
    hipMemsetAsync(out, 0, out_size, stream);

    // prep_misc total elements: borders 546304 + xdp ring 198656 + weights 534528
    const int prep_total = 546304 + 198656 + 534528;
    prep_misc<<<dim3((prep_total + 255) / 256), 256, 0, stream>>>(
        xpad1, hpa, hpb, xdp, ow0, ow1, ow2, ow3, weight,
        wb0, wb1, wb2, wb3, wbd);
    pack_all<<<dim3(288, 11, 4), 256, 0, stream>>>(extra, flow1, flow2, x, xpad1, xdp);

    conv_mfma<224, 7><<<dim3(144, 4), 256, 0, stream>>>(xpad1, wb0, ob0, hpa);
    conv_mfma<64, 2><<<dim3(144, 4), 256, 0, stream>>>(hpa, wb1, ob1, hpb);
    conv_mfma<64, 2><<<dim3(144, 4), 256, 0, stream>>>(hpb, wb2, ob2, hpa);
    conv4_mfma<<<dim3(144, 4, 7), 256, 0, stream>>>(hpa, wb3, ob3, offpair,
                                                    maskbuf, flow1, flow2);
    deform_mfma<<<dim3(1152), 256, 0, stream>>>(xdp, offpair, maskbuf, wbd, bias, out);
}